// Round 1
// baseline (200.946 us; speedup 1.0000x reference)
//
#include <hip/hip_runtime.h>

// Problem constants (from reference)
#define B 64
#define D 25000
#define K 16
#define H 128
#define E 256
#define Z 32
#define IN1 18        // 1 + K + 1
#define DTILE 40      // features per block; 625 blocks exactly
#define NW 4          // waves per 256-thread block

__device__ __forceinline__ void fma4(float4& acc, float s, const float4& w) {
    acc.x = fmaf(s, w.x, acc.x);
    acc.y = fmaf(s, w.y, acc.y);
    acc.z = fmaf(s, w.z, acc.z);
    acc.w = fmaf(s, w.w, acc.w);
}

// Main kernel: per (b,d) compute relu(relu(x*w0 + G_d) @ W2 + b2) * mask, sum over d.
// G_d = feat_emb[d,:]@W1[1:17,:] + feat_bias[d]*W1[17,:] + b1  (d-only -> computed once per tile)
__global__ __launch_bounds__(256) void partial_main_kernel(
    const float* __restrict__ x, const int* __restrict__ mask,
    const float* __restrict__ feat_emb, const float* __restrict__ feat_bias,
    const float* __restrict__ W1, const float* __restrict__ b1,
    const float* __restrict__ W2, const float* __restrict__ b2,
    float* __restrict__ c_out)
{
    __shared__ float sW1[IN1 * H];     // 2304 f  (row 0 = w0)
    __shared__ float sW2[H * K];       // 2048 f
    __shared__ float sB2[K];
    __shared__ float sFE[DTILE * K];   // feat_emb tile
    __shared__ float sFB[DTILE];       // feat_bias tile
    __shared__ float sG[DTILE * H];    // 5120 f (20 KB); reused as reduction scratch
    __shared__ float sXT[DTILE * B];   // x transposed [dd][b]
    __shared__ float sMT[DTILE * B];   // mask as float [dd][b]

    const int t  = threadIdx.x;
    const int d0 = blockIdx.x * DTILE;

    // ---- stage weights + input tiles ----
    for (int i = t; i < IN1 * H; i += 256) sW1[i] = W1[i];
    for (int i = t; i < H * K;  i += 256) sW2[i] = W2[i];
    if (t < K) sB2[t] = b2[t];
    for (int i = t; i < DTILE * K; i += 256) sFE[i] = feat_emb[d0 * K + i];
    if (t < DTILE) sFB[t] = feat_bias[d0 + t];
    for (int i = t; i < DTILE * B; i += 256) {
        int b  = i / DTILE;
        int dd = i - b * DTILE;
        sXT[dd * B + b] = x[b * D + d0 + dd];
        sMT[dd * B + b] = (float)mask[b * D + d0 + dd];
    }
    __syncthreads();

    // ---- G tile: 5120 outputs, 17 FMA each ----
    for (int i = t; i < DTILE * H; i += 256) {
        int dd = i >> 7;
        int h  = i & (H - 1);
        float acc = fmaf(sFB[dd], sW1[17 * H + h], b1[h]);
        #pragma unroll
        for (int k = 0; k < K; ++k)
            acc = fmaf(sFE[dd * K + k], sW1[(1 + k) * H + h], acc);
        sG[i] = acc;
    }
    __syncthreads();

    // ---- main loop: lanes = samples b, waves split d's, 2-wide d blocking ----
    const int lane = t & 63;
    const int wv   = t >> 6;

    float4 cacc0 = make_float4(0.f, 0.f, 0.f, 0.f);
    float4 cacc1 = cacc0, cacc2 = cacc0, cacc3 = cacc0;

    const float4* W2v = (const float4*)sW2;   // [H][4]
    const float4* B2v = (const float4*)sB2;

    for (int dd = 2 * wv; dd < DTILE; dd += 2 * NW) {
        const float xv0 = sXT[dd * B + lane];
        const float xv1 = sXT[(dd + 1) * B + lane];
        const float mv0 = sMT[dd * B + lane];
        const float mv1 = sMT[(dd + 1) * B + lane];
        const float* G0 = &sG[dd * H];
        const float* G1 = &sG[(dd + 1) * H];

        float4 p0 = B2v[0], p1 = B2v[1], p2 = B2v[2], p3 = B2v[3];  // h2 for d=dd
        float4 q0 = B2v[0], q1 = B2v[1], q2 = B2v[2], q3 = B2v[3];  // h2 for d=dd+1

        #pragma unroll 4
        for (int h = 0; h < H; ++h) {
            const float w0h = sW1[h];
            const float h10 = fmaxf(fmaf(xv0, w0h, G0[h]), 0.f);
            const float h11 = fmaxf(fmaf(xv1, w0h, G1[h]), 0.f);
            const float4 w2a = W2v[h * 4 + 0];
            const float4 w2b = W2v[h * 4 + 1];
            const float4 w2c = W2v[h * 4 + 2];
            const float4 w2d = W2v[h * 4 + 3];
            fma4(p0, h10, w2a); fma4(p1, h10, w2b);
            fma4(p2, h10, w2c); fma4(p3, h10, w2d);
            fma4(q0, h11, w2a); fma4(q1, h11, w2b);
            fma4(q2, h11, w2c); fma4(q3, h11, w2d);
        }
        // relu + mask + accumulate
        cacc0.x += mv0 * fmaxf(p0.x, 0.f) + mv1 * fmaxf(q0.x, 0.f);
        cacc0.y += mv0 * fmaxf(p0.y, 0.f) + mv1 * fmaxf(q0.y, 0.f);
        cacc0.z += mv0 * fmaxf(p0.z, 0.f) + mv1 * fmaxf(q0.z, 0.f);
        cacc0.w += mv0 * fmaxf(p0.w, 0.f) + mv1 * fmaxf(q0.w, 0.f);
        cacc1.x += mv0 * fmaxf(p1.x, 0.f) + mv1 * fmaxf(q1.x, 0.f);
        cacc1.y += mv0 * fmaxf(p1.y, 0.f) + mv1 * fmaxf(q1.y, 0.f);
        cacc1.z += mv0 * fmaxf(p1.z, 0.f) + mv1 * fmaxf(q1.z, 0.f);
        cacc1.w += mv0 * fmaxf(p1.w, 0.f) + mv1 * fmaxf(q1.w, 0.f);
        cacc2.x += mv0 * fmaxf(p2.x, 0.f) + mv1 * fmaxf(q2.x, 0.f);
        cacc2.y += mv0 * fmaxf(p2.y, 0.f) + mv1 * fmaxf(q2.y, 0.f);
        cacc2.z += mv0 * fmaxf(p2.z, 0.f) + mv1 * fmaxf(q2.z, 0.f);
        cacc2.w += mv0 * fmaxf(p2.w, 0.f) + mv1 * fmaxf(q2.w, 0.f);
        cacc3.x += mv0 * fmaxf(p3.x, 0.f) + mv1 * fmaxf(q3.x, 0.f);
        cacc3.y += mv0 * fmaxf(p3.y, 0.f) + mv1 * fmaxf(q3.y, 0.f);
        cacc3.z += mv0 * fmaxf(p3.z, 0.f) + mv1 * fmaxf(q3.z, 0.f);
        cacc3.w += mv0 * fmaxf(p3.w, 0.f) + mv1 * fmaxf(q3.w, 0.f);
    }

    // ---- block reduction across 4 waves (reuse sG; pad stride 17 vs bank conflicts) ----
    __syncthreads();   // everyone done reading sG
    float* red = sG;   // need 4*64*17 = 4352 <= 5120
    {
        const int base = (wv * 64 + lane) * 17;
        red[base +  0] = cacc0.x; red[base +  1] = cacc0.y;
        red[base +  2] = cacc0.z; red[base +  3] = cacc0.w;
        red[base +  4] = cacc1.x; red[base +  5] = cacc1.y;
        red[base +  6] = cacc1.z; red[base +  7] = cacc1.w;
        red[base +  8] = cacc2.x; red[base +  9] = cacc2.y;
        red[base + 10] = cacc2.z; red[base + 11] = cacc2.w;
        red[base + 12] = cacc3.x; red[base + 13] = cacc3.y;
        red[base + 14] = cacc3.z; red[base + 15] = cacc3.w;
    }
    __syncthreads();
    for (int i = t; i < B * K; i += 256) {
        int b = i >> 4, k = i & 15;
        float v = red[(0 * 64 + b) * 17 + k] + red[(1 * 64 + b) * 17 + k]
                + red[(2 * 64 + b) * 17 + k] + red[(3 * 64 + b) * 17 + k];
        atomicAdd(&c_out[i], v);
    }
}

// Encoder: one block per sample b. c[16] -> relu(@We1+be1)[256] -> @We2+be2 [64] -> mu/logvar
__global__ __launch_bounds__(256) void partial_enc_kernel(
    const float* __restrict__ c, const float* __restrict__ We1,
    const float* __restrict__ be1, const float* __restrict__ We2,
    const float* __restrict__ be2, float* __restrict__ out)
{
    const int b = blockIdx.x;
    const int t = threadIdx.x;
    __shared__ float sc[K];
    __shared__ float st1[E];
    __shared__ float red[256];

    if (t < K) sc[t] = c[b * K + t];
    __syncthreads();

    {
        float acc = be1[t];
        #pragma unroll
        for (int k = 0; k < K; ++k)
            acc = fmaf(sc[k], We1[k * E + t], acc);
        st1[t] = fmaxf(acc, 0.f);
    }
    __syncthreads();

    const int j = t & 63, seg = t >> 6;
    float acc = 0.f;
    #pragma unroll 4
    for (int e = seg * 64; e < seg * 64 + 64; ++e)
        acc = fmaf(st1[e], We2[e * 64 + j], acc);
    red[t] = acc;
    __syncthreads();

    if (t < 64) {
        float v = red[j] + red[64 + j] + red[128 + j] + red[192 + j] + be2[j];
        if (j < Z) out[b * Z + j] = v;                 // mu
        else       out[B * Z + b * Z + (j - Z)] = v;   // logvar
    }
}

extern "C" void kernel_launch(void* const* d_in, const int* in_sizes, int n_in,
                              void* d_out, int out_size, void* d_ws, size_t ws_size,
                              hipStream_t stream) {
    const float* x         = (const float*)d_in[0];
    const int*   mask      = (const int*)  d_in[1];
    const float* feat_emb  = (const float*)d_in[2];
    const float* feat_bias = (const float*)d_in[3];
    const float* W1        = (const float*)d_in[4];
    const float* b1        = (const float*)d_in[5];
    const float* W2        = (const float*)d_in[6];
    const float* b2        = (const float*)d_in[7];
    const float* We1       = (const float*)d_in[8];
    const float* be1       = (const float*)d_in[9];
    const float* We2       = (const float*)d_in[10];
    const float* be2       = (const float*)d_in[11];

    float* c_ws = (float*)d_ws;   // B*K accumulator, must be zeroed (ws poisoned 0xAA)
    hipMemsetAsync(c_ws, 0, B * K * sizeof(float), stream);

    partial_main_kernel<<<D / DTILE, 256, 0, stream>>>(
        x, mask, feat_emb, feat_bias, W1, b1, W2, b2, c_ws);
    partial_enc_kernel<<<B, 256, 0, stream>>>(
        c_ws, We1, be1, We2, be2, (float*)d_out);
}

// Round 2
// 132.961 us; speedup vs baseline: 1.5113x; 1.5113x over previous
//
#include <hip/hip_runtime.h>
#include <hip/hip_bf16.h>

// Problem constants
#define B 64
#define D 25000
#define K 16
#define H 128
#define E 256
#define Z 32
#define DTILE 25      // 1000 blocks, all resident at 4 blocks/CU
#define XSTR 65       // sX padded stride (65%32==1 -> conflict-free strided writes)
#define MSTR 68       // sM padded stride (%4==0 for float4 reads)

typedef __attribute__((ext_vector_type(8))) short short8;
typedef __attribute__((ext_vector_type(4))) float f32x4;

__device__ __forceinline__ unsigned short f2bf(float f) {
    union { float f; unsigned u; } v; v.f = f;
    unsigned u = v.u + 0x7FFF + ((v.u >> 16) & 1);
    return (unsigned short)(u >> 16);
}
__device__ __forceinline__ float bf2f(unsigned short s) {
    union { unsigned u; float f; } v; v.u = (unsigned)s << 16;
    return v.f;
}

// Per (b,d): h1 = relu(x*w0 + G_d)  [VALU, rank-1 trick]
//            h2 = relu(h1 @ W2 + b2) [MFMA 16x16x32 bf16 + bf16 residual of W2]
//            c += mask * h2          [VALU epilogue, fp32]
__global__ __launch_bounds__(256, 4) void partial_main_kernel(
    const float* __restrict__ x, const int* __restrict__ mask,
    const float* __restrict__ feat_emb, const float* __restrict__ feat_bias,
    const float* __restrict__ W1, const float* __restrict__ b1,
    const float* __restrict__ W2, const float* __restrict__ b2,
    float* __restrict__ c_out)
{
    __shared__ __align__(16) float sW1[18 * H];      // 2304 f (row 0 = w0)
    __shared__ __align__(16) float sG[DTILE * H];    // 3200 f; first 2048 alias W2raw in phase 1/2
    __shared__ __align__(16) float sFE[DTILE * K];
    __shared__ float sFB[DTILE];
    __shared__ __align__(16) float sX[DTILE * XSTR];
    __shared__ __align__(16) float sM[DTILE * MSTR];

    const int t    = threadIdx.x;
    const int d0   = blockIdx.x * DTILE;
    const int lane = t & 63;
    const int wv   = t >> 6;        // wave -> M-tile of 16 samples
    const int g    = lane >> 4;     // quad group
    const int n    = lane & 15;     // MFMA col (output k) / A-row m

    // ---- phase 1: stage raw tiles (coalesced global reads) ----
    for (int i = t; i < 18 * H; i += 256) sW1[i] = W1[i];
    for (int i = t; i < H * K;  i += 256) sG[i]  = W2[i];          // W2 raw, aliased
    for (int i = t; i < DTILE * K; i += 256) sFE[i] = feat_emb[d0 * K + i];
    if (t < DTILE) sFB[t] = feat_bias[d0 + t];
    for (int i = t; i < DTILE * B; i += 256) {
        int bb = i / DTILE, dd = i - bb * DTILE;       // dd fast -> coalesced global
        sX[dd * XSTR + bb] = x[bb * D + d0 + dd];
        sM[dd * MSTR + bb] = (float)mask[bb * D + d0 + dd];
    }
    __syncthreads();

    // ---- phase 2: build per-lane B-fragments (W2 bf16 + residual) and w0 regs ----
    short8 Bf1[4], Bf2[4];
    #pragma unroll
    for (int s = 0; s < 4; ++s) {
        union { short8 v; unsigned short e[8]; } u1, u2;
        #pragma unroll
        for (int j = 0; j < 8; ++j) {
            int k = s * 32 + g * 8 + j;                // B[k][n], k=(lane>>4)*8+j (+32s)
            float w = sG[k * K + n];                   // W2 raw from alias
            unsigned short hi = f2bf(w);
            u1.e[j] = hi;
            u2.e[j] = f2bf(w - bf2f(hi));
        }
        Bf1[s] = u1.v; Bf2[s] = u2.v;
    }
    float w0r[4][8];
    #pragma unroll
    for (int s = 0; s < 4; ++s) {
        const float4* wp = (const float4*)&sW1[s * 32 + g * 8];
        float4 a0 = wp[0], a1 = wp[1];
        w0r[s][0] = a0.x; w0r[s][1] = a0.y; w0r[s][2] = a0.z; w0r[s][3] = a0.w;
        w0r[s][4] = a1.x; w0r[s][5] = a1.y; w0r[s][6] = a1.z; w0r[s][7] = a1.w;
    }
    const float b2n = b2[n];
    __syncthreads();   // all waves done reading W2raw alias

    // ---- phase 3: G tile (overwrites W2raw alias) ----
    for (int i = t; i < DTILE * H; i += 256) {
        int dd = i >> 7, h = i & (H - 1);
        float acc = fmaf(sFB[dd], sW1[17 * H + h], b1[h]);
        #pragma unroll
        for (int k = 0; k < K; ++k)
            acc = fmaf(sFE[dd * K + k], sW1[(1 + k) * H + h], acc);
        sG[i] = acc;
    }
    __syncthreads();

    // ---- phase 4: per-d MFMA loop ----
    f32x4 cacc = {0.f, 0.f, 0.f, 0.f};
    const int xoff = wv * 16 + n;       // this lane's sample for A rows
    const int moff = wv * 16 + g * 4;   // this lane's 4 C rows

    for (int dd = 0; dd < DTILE; ++dd) {
        const float xv = sX[dd * XSTR + xoff];
        f32x4 c1 = {0.f, 0.f, 0.f, 0.f};
        f32x4 c2 = {0.f, 0.f, 0.f, 0.f};
        #pragma unroll
        for (int s = 0; s < 4; ++s) {
            const float4* gp = (const float4*)&sG[dd * H + s * 32 + g * 8];
            const float4 g0 = gp[0], g1 = gp[1];
            float h0 = fmaxf(fmaf(xv, w0r[s][0], g0.x), 0.f);
            float h1 = fmaxf(fmaf(xv, w0r[s][1], g0.y), 0.f);
            float h2 = fmaxf(fmaf(xv, w0r[s][2], g0.z), 0.f);
            float h3 = fmaxf(fmaf(xv, w0r[s][3], g0.w), 0.f);
            float h4 = fmaxf(fmaf(xv, w0r[s][4], g1.x), 0.f);
            float h5 = fmaxf(fmaf(xv, w0r[s][5], g1.y), 0.f);
            float h6 = fmaxf(fmaf(xv, w0r[s][6], g1.z), 0.f);
            float h7 = fmaxf(fmaf(xv, w0r[s][7], g1.w), 0.f);
            union { short8 v; unsigned u[4]; } a;
            union { __hip_bfloat162 h; unsigned u; } cv;
            cv.h = __float22bfloat162_rn(make_float2(h0, h1)); a.u[0] = cv.u;
            cv.h = __float22bfloat162_rn(make_float2(h2, h3)); a.u[1] = cv.u;
            cv.h = __float22bfloat162_rn(make_float2(h4, h5)); a.u[2] = cv.u;
            cv.h = __float22bfloat162_rn(make_float2(h6, h7)); a.u[3] = cv.u;
            c1 = __builtin_amdgcn_mfma_f32_16x16x32_bf16(a.v, Bf1[s], c1, 0, 0, 0);
            c2 = __builtin_amdgcn_mfma_f32_16x16x32_bf16(a.v, Bf2[s], c2, 0, 0, 0);
        }
        const float4 mv = *(const float4*)&sM[dd * MSTR + moff];
        float p0 = c1[0] + c2[0] + b2n;
        float p1 = c1[1] + c2[1] + b2n;
        float p2 = c1[2] + c2[2] + b2n;
        float p3 = c1[3] + c2[3] + b2n;
        cacc[0] = fmaf(mv.x, fmaxf(p0, 0.f), cacc[0]);
        cacc[1] = fmaf(mv.y, fmaxf(p1, 0.f), cacc[1]);
        cacc[2] = fmaf(mv.z, fmaxf(p2, 0.f), cacc[2]);
        cacc[3] = fmaf(mv.w, fmaxf(p3, 0.f), cacc[3]);
    }

    #pragma unroll
    for (int r = 0; r < 4; ++r)
        atomicAdd(&c_out[(moff + r) * K + n], cacc[r]);
}

// Encoder: one block per sample b. c[16] -> relu(@We1+be1)[256] -> @We2+be2 [64]
__global__ __launch_bounds__(256) void partial_enc_kernel(
    const float* __restrict__ c, const float* __restrict__ We1,
    const float* __restrict__ be1, const float* __restrict__ We2,
    const float* __restrict__ be2, float* __restrict__ out)
{
    const int b = blockIdx.x;
    const int t = threadIdx.x;
    __shared__ float sc[K];
    __shared__ float st1[E];
    __shared__ float red[256];

    if (t < K) sc[t] = c[b * K + t];
    __syncthreads();

    {
        float acc = be1[t];
        #pragma unroll
        for (int k = 0; k < K; ++k)
            acc = fmaf(sc[k], We1[k * E + t], acc);
        st1[t] = fmaxf(acc, 0.f);
    }
    __syncthreads();

    const int j = t & 63, seg = t >> 6;
    float acc = 0.f;
    #pragma unroll 4
    for (int e = seg * 64; e < seg * 64 + 64; ++e)
        acc = fmaf(st1[e], We2[e * 64 + j], acc);
    red[t] = acc;
    __syncthreads();

    if (t < 64) {
        float v = red[j] + red[64 + j] + red[128 + j] + red[192 + j] + be2[j];
        if (j < Z) out[b * Z + j] = v;                 // mu
        else       out[B * Z + b * Z + (j - Z)] = v;   // logvar
    }
}

extern "C" void kernel_launch(void* const* d_in, const int* in_sizes, int n_in,
                              void* d_out, int out_size, void* d_ws, size_t ws_size,
                              hipStream_t stream) {
    const float* x         = (const float*)d_in[0];
    const int*   mask      = (const int*)  d_in[1];
    const float* feat_emb  = (const float*)d_in[2];
    const float* feat_bias = (const float*)d_in[3];
    const float* W1        = (const float*)d_in[4];
    const float* b1        = (const float*)d_in[5];
    const float* W2        = (const float*)d_in[6];
    const float* b2        = (const float*)d_in[7];
    const float* We1       = (const float*)d_in[8];
    const float* be1       = (const float*)d_in[9];
    const float* We2       = (const float*)d_in[10];
    const float* be2       = (const float*)d_in[11];

    float* c_ws = (float*)d_ws;   // B*K accumulator (ws is poisoned 0xAA each call)
    hipMemsetAsync(c_ws, 0, B * K * sizeof(float), stream);

    partial_main_kernel<<<D / DTILE, 256, 0, stream>>>(
        x, mask, feat_emb, feat_bias, W1, b1, W2, b2, c_ws);
    partial_enc_kernel<<<B, 256, 0, stream>>>(
        c_ws, We1, be1, We2, be2, (float*)d_out);
}